// Round 15
// baseline (2284.114 us; speedup 1.0000x reference)
//
#include <hip/hip_runtime.h>
#include <stdint.h>

typedef _Float16 f16;
typedef _Float16 f16x8 __attribute__((ext_vector_type(8)));
typedef float f32x4 __attribute__((ext_vector_type(4)));

#define INF_F __builtin_inff()
#define INF_I 0x7fffffff
#define KM 24            // merge candidate margin
#define SCALE 262144.0f  // 2^18 fixed-point scale

__device__ __forceinline__ bool lexLess(float s1, int n1, float s2, int n2) {
    return (s1 < s2) || (s1 == s2 && n1 < n2);
}
__device__ __forceinline__ bool lexLessI(int s1, int n1, int s2, int n2) {
    return (s1 < s2) || (s1 == s2 && n1 < n2);
}

__device__ __forceinline__ uint4 pack8(const float4 a, const float4 b) {
    const auto p0 = __builtin_amdgcn_cvt_pkrtz(a.x, a.y);
    const auto p1 = __builtin_amdgcn_cvt_pkrtz(a.z, a.w);
    const auto p2 = __builtin_amdgcn_cvt_pkrtz(b.x, b.y);
    const auto p3 = __builtin_amdgcn_cvt_pkrtz(b.z, b.w);
    uint4 u;
    u.x = __builtin_bit_cast(unsigned, p0);
    u.y = __builtin_bit_cast(unsigned, p1);
    u.z = __builtin_bit_cast(unsigned, p2);
    u.w = __builtin_bit_cast(unsigned, p3);
    return u;
}
__device__ __forceinline__ uint2 pack4(const float4 a) {
    const auto p0 = __builtin_amdgcn_cvt_pkrtz(a.x, a.y);
    const auto p1 = __builtin_amdgcn_cvt_pkrtz(a.z, a.w);
    uint2 u;
    u.x = __builtin_bit_cast(unsigned, p0);
    u.y = __builtin_bit_cast(unsigned, p1);
    return u;
}
__device__ __forceinline__ float ssum(const float4 v) {
    return fmaf(v.x, v.x, fmaf(v.y, v.y, fmaf(v.z, v.z, v.w * v.w)));
}

// ---------------------------------------------------------------------------
// Kernel 1: deep-burst streaming scores + per-block top-16 per batch row.
// 8 waves (512 threads); tile = 32 rep rows. Wave w owns rows [4w,4w+4):
// its burst = 8 KB CONTIGUOUS (4 rows x 2 KB, 8x dwordx4-wave loads) into 32
// VGPRs — the exact pattern the R14 ablation measured at ~5.5 TB/s. Bursts
// are issued one tile ahead and stay in flight across the whole compute
// phase (16 waves/CU x 8 KB = 128 KB/CU outstanding). Pack f32->f16 +
// XOR-swizzled ds_write late. Compute: k-split 8 (A-slice 32 VGPR from
// L2-hot brep), B-frags via swizzled ds_read_b128 from a SINGLE 32 KB ybuf
// (reads pre-BAR1, writes post-BAR1 -> no double buffer needed). Exact
// int32 atomic fold into slds; in-phase 32-iter scan by rotating wave.
// ---------------------------------------------------------------------------
__global__ __launch_bounds__(512, 4) void dist_topk_kernel(
    const float* __restrict__ reps, const float* __restrict__ brep,
    float* __restrict__ cs, int* __restrict__ ci,
    int N, int TT, int NBLK)
{
    __shared__ __align__(16) char ybuf[32 * 1024];   // 32 KB f16 tile (swizzled)
    __shared__ int slds[32][64];                     // 8 KB int dot partials
    __shared__ int ynI[2][32];                       // norms (write t+1 / read t)
    __shared__ int topdI[16][64];
    __shared__ int topiI[16][64];
    __shared__ int thrS[64], thrnS[64], cntS[64];

    const int tid = threadIdx.x;
    const int w = tid >> 6, lane = tid & 63;
    const int li = lane & 15, q = lane >> 4;
    const int b = blockIdx.x;

    // ---- A-fragments for this wave's k-slice (32 VGPR), from L2-hot brep ----
    // a[ks2][mt] = A[m=mt*16+li][k = 64w + 32ks2 + 8q + j], j=0..7
    uint4 a[2][4];
    #pragma unroll
    for (int ks2 = 0; ks2 < 2; ks2++)
        #pragma unroll
        for (int mt = 0; mt < 4; mt++) {
            const float* src = brep + (mt * 16 + li) * 512 + 64 * w + 32 * ks2 + 8 * q;
            a[ks2][mt] = pack8(*(const float4*)(src), *(const float4*)(src + 4));
        }

    if (tid < 64) { thrS[tid] = INF_I; thrnS[tid] = INF_I; cntS[tid] = 0; }
    for (int i = tid; i < 32 * 64; i += 512) ((int*)slds)[i] = 0;

    float4 st[8];
    // issue tile t's burst: wave-contiguous 8 KB = rows [t*32+4w, +4)
    auto issue = [&](long t) {
        const long r0 = t * 32 + 4 * w;
        #pragma unroll
        for (int i = 0; i < 8; i++) {
            long rr = r0 + (i >> 1); if (rr >= N) rr = N - 1;
            st[i] = *(const float4*)((const char*)(reps + rr * 512)
                                     + (i & 1) * 1024 + lane * 16);
        }
    };
    // pack + swizzled LDS write + ynorms (fixed shfl tree; deterministic)
    auto cvt_write = [&](int yi) {
        #pragma unroll
        for (int i = 0; i < 8; i++) {
            const int ri = 4 * w + (i >> 1);
            const uint2 u = pack4(st[i]);
            *(uint2*)(ybuf + ri * 1024 +
                      (((i & 1) * 512 + lane * 8) ^ ((ri & 7) << 4))) = u;
        }
        float s0 = ssum(st[0]) + ssum(st[1]);
        float s1 = ssum(st[2]) + ssum(st[3]);
        float s2 = ssum(st[4]) + ssum(st[5]);
        float s3 = ssum(st[6]) + ssum(st[7]);
        #pragma unroll
        for (int d = 1; d < 64; d <<= 1) {
            s0 += __shfl_xor(s0, d); s1 += __shfl_xor(s1, d);
            s2 += __shfl_xor(s2, d); s3 += __shfl_xor(s3, d);
        }
        if (lane == 0) {
            ynI[yi][4 * w + 0] = __float2int_rn(s0 * SCALE);
            ynI[yi][4 * w + 1] = __float2int_rn(s1 * SCALE);
            ynI[yi][4 * w + 2] = __float2int_rn(s2 * SCALE);
            ynI[yi][4 * w + 3] = __float2int_rn(s3 * SCALE);
        }
    };
    // exact per-block top-16 scan of the current tile; then zero slds
    auto scan = [&](int scp, long tp) {
        const long n0p = tp * 32;
        const int r = lane;
        volatile int* sb = &slds[0][0];
        volatile int* yv = &ynI[scp & 1][0];
        int thr = thrS[r], thrn = thrnS[r], cnt = cntS[r];
        for (int j = 0; j < 32; j++) {
            const long n = n0p + j;
            if (n >= N) break;
            const int s = yv[j] - 2 * sb[j * 64 + r];
            if (lexLessI(s, (int)n, thr, thrn)) {
                if (cnt < 16) {
                    topdI[cnt][r] = s; topiI[cnt][r] = (int)n; cnt++;
                    if (cnt == 16) {
                        int tv = topdI[0][r], tn = topiI[0][r];
                        #pragma unroll
                        for (int u = 1; u < 16; u++) {
                            int v = topdI[u][r], nn = topiI[u][r];
                            if (!lexLessI(v, nn, tv, tn)) { tv = v; tn = nn; }
                        }
                        thr = tv; thrn = tn;
                    }
                } else {
                    #pragma unroll
                    for (int u = 0; u < 16; u++)
                        if (topdI[u][r] == thr && topiI[u][r] == thrn) {
                            topdI[u][r] = s; topiI[u][r] = (int)n; break;
                        }
                    int tv = topdI[0][r], tn = topiI[0][r];
                    #pragma unroll
                    for (int u = 1; u < 16; u++) {
                        int v = topdI[u][r], nn = topiI[u][r];
                        if (!lexLessI(v, nn, tv, tn)) { tv = v; tn = nn; }
                    }
                    thr = tv; thrn = tn;
                }
            }
        }
        thrS[r] = thr; thrnS[r] = thrn; cntS[r] = cnt;
        for (int e2 = lane; e2 < 32 * 64; e2 += 64) sb[e2] = 0;
    };

    // ---- prologue: stage tile b fully ----
    issue(b);
    cvt_write(0);
    __syncthreads();

    int sc = 0;
    for (long t = b; t < TT; t += NBLK, ++sc) {
        const bool haveNext = (t + NBLK) < TT;

        // (1) issue next tile's 8 KB burst; stays in flight through compute
        if (haveNext) issue(t + NBLK);
        __builtin_amdgcn_sched_barrier(0);

        // (2) compute tile t from swizzled ybuf; fold exact-int into slds
        #pragma unroll
        for (int nsub = 0; nsub < 2; nsub++) {
            f32x4 acc0 = {0.f,0.f,0.f,0.f}, acc1 = {0.f,0.f,0.f,0.f};
            f32x4 acc2 = {0.f,0.f,0.f,0.f}, acc3 = {0.f,0.f,0.f,0.f};
            #pragma unroll
            for (int ks2 = 0; ks2 < 2; ks2++) {
                const int row = nsub * 16 + li;
                const int col = 128 * w + 64 * ks2 + 16 * q;
                const f16x8 bf = *(const f16x8*)(ybuf + row * 1024 +
                                                 (col ^ ((row & 7) << 4)));
                acc0 = __builtin_amdgcn_mfma_f32_16x16x32_f16(__builtin_bit_cast(f16x8, a[ks2][0]), bf, acc0, 0, 0, 0);
                acc1 = __builtin_amdgcn_mfma_f32_16x16x32_f16(__builtin_bit_cast(f16x8, a[ks2][1]), bf, acc1, 0, 0, 0);
                acc2 = __builtin_amdgcn_mfma_f32_16x16x32_f16(__builtin_bit_cast(f16x8, a[ks2][2]), bf, acc2, 0, 0, 0);
                acc3 = __builtin_amdgcn_mfma_f32_16x16x32_f16(__builtin_bit_cast(f16x8, a[ks2][3]), bf, acc3, 0, 0, 0);
            }
            const int nloc = nsub * 16 + li;
            #pragma unroll
            for (int jj = 0; jj < 4; jj++) {
                atomicAdd(&slds[nloc][ 0 + 4 * q + jj], __float2int_rn(acc0[jj] * SCALE));
                atomicAdd(&slds[nloc][16 + 4 * q + jj], __float2int_rn(acc1[jj] * SCALE));
                atomicAdd(&slds[nloc][32 + 4 * q + jj], __float2int_rn(acc2[jj] * SCALE));
                atomicAdd(&slds[nloc][48 + 4 * q + jj], __float2int_rn(acc3[jj] * SCALE));
            }
        }

        // (3) BAR1: all atomics + ybuf reads of tile t complete
        asm volatile("s_waitcnt lgkmcnt(0)");
        __builtin_amdgcn_sched_barrier(0);
        __builtin_amdgcn_s_barrier();
        __builtin_amdgcn_sched_barrier(0);

        // (4) rotating wave scans tile t; all waves stage tile t+1 into ybuf
        if (w == (sc & 7)) scan(sc, t);
        if (haveNext) cvt_write((sc + 1) & 1);

        // (5) BAR2: scan state + staged tile visible for next phase
        asm volatile("s_waitcnt lgkmcnt(0)");
        __builtin_amdgcn_sched_barrier(0);
        __builtin_amdgcn_s_barrier();
        __builtin_amdgcn_sched_barrier(0);
    }

    __syncthreads();
    if (tid < 64) {
        const int c = cntS[tid];
        const size_t base = ((size_t)b * 64 + tid) * 16;
        for (int j = 0; j < 16; j++) {
            cs[base + j] = (j < c) ? ((float)topdI[j][tid] * (1.0f / SCALE)) : INF_F;
            ci[base + j] = (j < c) ? topiI[j][tid] : INF_I;
        }
    }
}

// ---------------------------------------------------------------------------
// Kernel 2 (R10 verbatim): approx global top-24 merge, fp64 exact recompute,
// exact sort -> top-16, softmax weights, action gather, outputs.
// ---------------------------------------------------------------------------
__global__ __launch_bounds__(256) void merge_kernel(
    const float* __restrict__ cs, const int* __restrict__ ci,
    const float* __restrict__ brep, const float* __restrict__ reps,
    const float* __restrict__ acts,
    float* __restrict__ out, int NLISTS, int N, int BA)
{
    const int r = blockIdx.x;
    const int tid = threadIdx.x;
    __shared__ __align__(16) float xrow[512];
    __shared__ float S1s[256 * KM];
    __shared__ int   S1i[256 * KM];
    __shared__ float S2s[32 * KM];
    __shared__ int   S2i[32 * KM];
    __shared__ double fd[KM];
    __shared__ int    fn[KM];

    if (tid < 128)
        *(float4*)(&xrow[tid * 4]) = *(const float4*)(&brep[(size_t)r * 512 + tid * 4]);

    float ls[KM]; int li[KM];
    #pragma unroll
    for (int j = 0; j < KM; j++) { ls[j] = INF_F; li[j] = INF_I; }
    float mv = INF_F; int mn = INF_I; int mp = 0;
    const int total = NLISTS * 16;
    for (int e = tid; e < total; e += 256) {
        const int blk = e >> 4, j = e & 15;
        const size_t a = (size_t)blk * 1024 + (size_t)r * 16 + j;
        const float s = cs[a]; const int n = ci[a];
        if (lexLess(s, n, mv, mn)) {
            ls[mp] = s; li[mp] = n;
            mv = ls[0]; mn = li[0]; mp = 0;
            #pragma unroll
            for (int u = 1; u < KM; u++)
                if (!lexLess(ls[u], li[u], mv, mn)) { mv = ls[u]; mn = li[u]; mp = u; }
        }
    }
    #pragma unroll
    for (int j = 0; j < KM; j++) { S1s[tid * KM + j] = ls[j]; S1i[tid * KM + j] = li[j]; }
    __syncthreads();

    if (tid < 32) {
        #pragma unroll
        for (int j = 0; j < KM; j++) { ls[j] = INF_F; li[j] = INF_I; }
        mv = INF_F; mn = INF_I; mp = 0;
        for (int e = tid * 8 * KM; e < (tid * 8 + 8) * KM; e++) {
            const float s = S1s[e]; const int n = S1i[e];
            if (lexLess(s, n, mv, mn)) {
                ls[mp] = s; li[mp] = n;
                mv = ls[0]; mn = li[0]; mp = 0;
                #pragma unroll
                for (int u = 1; u < KM; u++)
                    if (!lexLess(ls[u], li[u], mv, mn)) { mv = ls[u]; mn = li[u]; mp = u; }
            }
        }
        #pragma unroll
        for (int j = 0; j < KM; j++) { S2s[tid * KM + j] = ls[j]; S2i[tid * KM + j] = li[j]; }
    }
    __syncthreads();

    if (tid == 0) {
        #pragma unroll
        for (int j = 0; j < KM; j++) { ls[j] = INF_F; li[j] = INF_I; }
        mv = INF_F; mn = INF_I; mp = 0;
        for (int e = 0; e < 32 * KM; e++) {
            const float s = S2s[e]; const int n = S2i[e];
            if (lexLess(s, n, mv, mn)) {
                ls[mp] = s; li[mp] = n;
                mv = ls[0]; mn = li[0]; mp = 0;
                #pragma unroll
                for (int u = 1; u < KM; u++)
                    if (!lexLess(ls[u], li[u], mv, mn)) { mv = ls[u]; mn = li[u]; mp = u; }
            }
        }
        for (int j = 0; j < KM; j++) fn[j] = li[j];
    }
    __syncthreads();

    if (tid < KM) {
        const int n = fn[tid];
        double d = 1.0e300;
        if (n >= 0 && n < N) {
            double d0a = 0.0, d1a = 0.0, d2a = 0.0, d3a = 0.0;
            const float* yp = reps + (size_t)n * 512;
            for (int i = 0; i < 512; i += 4) {
                float4 yv = *(const float4*)(yp + i);
                double e0 = (double)xrow[i + 0] - (double)yv.x;
                double e1 = (double)xrow[i + 1] - (double)yv.y;
                double e2 = (double)xrow[i + 2] - (double)yv.z;
                double e3 = (double)xrow[i + 3] - (double)yv.w;
                d0a += e0 * e0; d1a += e1 * e1; d2a += e2 * e2; d3a += e3 * e3;
            }
            d = (d0a + d1a) + (d2a + d3a);
        }
        fd[tid] = d;
    }
    __syncthreads();

    if (tid == 0) {
        int ord[KM];
        for (int j = 0; j < KM; j++) ord[j] = j;
        for (int a = 0; a < 16; a++) {
            int best = a;
            for (int u = a + 1; u < KM; u++) {
                const int ou = ord[u], ob = ord[best];
                if (fd[ou] < fd[ob] || (fd[ou] == fd[ob] && fn[ou] < fn[ob])) best = u;
            }
            int tmp = ord[a]; ord[a] = ord[best]; ord[best] = tmp;
        }
        double dist[16];
        for (int j = 0; j < 16; j++) {
            double v = fd[ord[j]];
            dist[j] = sqrt(v > 0.0 ? v : 0.0);
        }
        double wv[16], wsum = 0.0;
        for (int j = 0; j < 16; j++) { wv[j] = exp(dist[0] - dist[j]); wsum += wv[j]; }
        for (int a = 0; a < 7; a++) {
            double s = 0.0;
            for (int j = 0; j < 16; j++)
                s += wv[j] * (double)acts[(size_t)fn[ord[j]] * 7 + a];
            out[r * 7 + a] = (float)(s / wsum);
        }
        for (int j = 0; j < 16; j++)
            out[BA + r * 16 + j] = (float)fn[ord[j]];
    }
}

extern "C" void kernel_launch(void* const* d_in, const int* in_sizes, int n_in,
                              void* d_out, int out_size, void* d_ws, size_t ws_size,
                              hipStream_t stream) {
    const float* brep = (const float*)d_in[0];
    const float* reps = (const float*)d_in[1];
    const float* acts = (const float*)d_in[2];
    const int D = 512;
    const int B = in_sizes[0] / D;   // 64
    const int N = in_sizes[1] / D;   // 500000
    float* out = (float*)d_out;

    // 512 blocks of 512 threads = 2 blocks/CU (49 KB LDS, <=128 VGPR).
    int NBLK = 512;
    const size_t perblk = (size_t)64 * 16 * 8;        // cs+ci bytes per block
    while (NBLK > 1 && (size_t)NBLK * perblk > ws_size) NBLK >>= 1;

    float* cs = (float*)d_ws;
    int* ci = (int*)((char*)d_ws + (size_t)NBLK * 64 * 16 * 4);

    const int TT = (N + 31) / 32;                     // 32-row tiles

    dist_topk_kernel<<<NBLK, 512, 0, stream>>>(reps, brep, cs, ci, N, TT, NBLK);
    merge_kernel<<<B, 256, 0, stream>>>(cs, ci, brep, reps, acts, out, NBLK, N, B * 7);
}

// Round 16
// 1299.467 us; speedup vs baseline: 1.7577x; 1.7577x over previous
//
#include <hip/hip_runtime.h>
#include <stdint.h>

typedef _Float16 f16;
typedef _Float16 f16x8 __attribute__((ext_vector_type(8)));
typedef float f32x4 __attribute__((ext_vector_type(4)));

#define INF_F __builtin_inff()
#define INF_I 0x7fffffff
#define KM 24            // merge candidate margin
#define SCALE 262144.0f  // 2^18 fixed-point scale

__device__ __forceinline__ bool lexLess(float s1, int n1, float s2, int n2) {
    return (s1 < s2) || (s1 == s2 && n1 < n2);
}
__device__ __forceinline__ bool lexLessI(int s1, int n1, int s2, int n2) {
    return (s1 < s2) || (s1 == s2 && n1 < n2);
}

__device__ __forceinline__ uint4 pack8(const float4 a, const float4 b) {
    const auto p0 = __builtin_amdgcn_cvt_pkrtz(a.x, a.y);
    const auto p1 = __builtin_amdgcn_cvt_pkrtz(a.z, a.w);
    const auto p2 = __builtin_amdgcn_cvt_pkrtz(b.x, b.y);
    const auto p3 = __builtin_amdgcn_cvt_pkrtz(b.z, b.w);
    uint4 u;
    u.x = __builtin_bit_cast(unsigned, p0);
    u.y = __builtin_bit_cast(unsigned, p1);
    u.z = __builtin_bit_cast(unsigned, p2);
    u.w = __builtin_bit_cast(unsigned, p3);
    return u;
}

// ---------------------------------------------------------------------------
// Kernel 1: k-split streaming scores + per-block top-16 per batch row.
// R10 structure with three fixes:
//  (a) amdgpu_waves_per_eu(4,4): pins the allocator to a 128-VGPR budget.
//      launch_bounds' 2nd arg is only a MIN; the compiler was choosing an
//      8-wave/64-VGPR target and spilling the 64-VGPR A array to scratch
//      (R10/11/13/15 all show VGPR_Count=64 + ~17MB spill WRITE_SIZE).
//  (b) tile = 32 rows with DOUBLE-BUFFERED slds -> ONE barrier per tile;
//      the rotating scan of tile t-1 overlaps compute of tile t.
//  (c) LDS 25.6 KB -> 4 independent blocks/CU (the strongest perf
//      correlate across rounds).
// 4 waves; wave w owns k-quarter [128w,128w+128), A-slice in 64 VGPRs from
// L2-hot brep; y loads direct global->VGPR, depth-1 rotated; exact int32
// atomic fold into slds (deterministic, order-free).
// ---------------------------------------------------------------------------
__global__ __launch_bounds__(256)
__attribute__((amdgpu_waves_per_eu(4, 4)))
void dist_topk_kernel(
    const float* __restrict__ reps, const float* __restrict__ brep,
    float* __restrict__ cs, int* __restrict__ ci,
    int N, int TT, int NBLK)
{
    __shared__ int slds[2][32][65];               // [buf][rep-row][64 dots + ynorm]
    __shared__ int topdI[16][64];
    __shared__ int topiI[16][64];
    __shared__ int thrS[64], thrnS[64], cntS[64];

    const int tid = threadIdx.x;
    const int w = tid >> 6, lane = tid & 63;
    const int li = lane & 15, q = lane >> 4;
    const int b = blockIdx.x;

    // ---- A-fragments for this wave's k-quarter (64 VGPR), from L2-hot brep
    // a[ks][mt] = A[m = mt*16 + li][k = 128w + 32ks + 8q + j], j=0..7
    uint4 a[4][4];
    #pragma unroll
    for (int ks = 0; ks < 4; ks++)
        #pragma unroll
        for (int mt = 0; mt < 4; mt++) {
            const float* src = brep + (mt * 16 + li) * 512 + 128 * w + 32 * ks + 8 * q;
            const float4 x0 = *(const float4*)(src);
            const float4 x1 = *(const float4*)(src + 4);
            a[ks][mt] = pack8(x0, x1);
        }

    if (tid < 64) { thrS[tid] = INF_I; thrnS[tid] = INF_I; cntS[tid] = 0; }
    for (int i = tid; i < 2 * 32 * 65; i += 256) ((int*)slds)[i] = 0;
    __syncthreads();

    // exact top-16 scan of tile with step-counter scp; then zero its buffer
    auto scan = [&](int scp) {
        const long n0p = ((long)b + (long)scp * NBLK) * 32;
        const int r = lane;
        volatile int* sb = &slds[scp & 1][0][0];
        int thr = thrS[r], thrn = thrnS[r], cnt = cntS[r];
        for (int j = 0; j < 32; j++) {
            const long n = n0p + j;
            if (n >= N) break;
            const int s = sb[j * 65 + 64] - 2 * sb[j * 65 + r];
            if (lexLessI(s, (int)n, thr, thrn)) {
                if (cnt < 16) {
                    topdI[cnt][r] = s; topiI[cnt][r] = (int)n; cnt++;
                    if (cnt == 16) {
                        int tv = topdI[0][r], tn = topiI[0][r];
                        #pragma unroll
                        for (int u = 1; u < 16; u++) {
                            int v = topdI[u][r], nn = topiI[u][r];
                            if (!lexLessI(v, nn, tv, tn)) { tv = v; tn = nn; }
                        }
                        thr = tv; thrn = tn;
                    }
                } else {
                    #pragma unroll
                    for (int u = 0; u < 16; u++)
                        if (topdI[u][r] == thr && topiI[u][r] == thrn) {
                            topdI[u][r] = s; topiI[u][r] = (int)n; break;
                        }
                    int tv = topdI[0][r], tn = topiI[0][r];
                    #pragma unroll
                    for (int u = 1; u < 16; u++) {
                        int v = topdI[u][r], nn = topiI[u][r];
                        if (!lexLessI(v, nn, tv, tn)) { tv = v; tn = nn; }
                    }
                    thr = tv; thrn = tn;
                }
            }
        }
        thrS[r] = thr; thrnS[r] = thrn; cntS[r] = cnt;
        for (int e2 = lane; e2 < 32 * 65; e2 += 64) sb[e2] = 0;
    };

    int sc = 0;
    for (long t = b; t < (long)TT; t += NBLK, sc++) {
        const int p = sc & 1;
        const long n0 = t * 32;

        #pragma unroll 1
        for (int nsub = 0; nsub < 2; nsub++) {
            const long rowl = n0 + nsub * 16 + li;
            const size_t rowc = (size_t)(rowl < N ? rowl : N - 1);
            const float* bp = reps + rowc * 512 + 128 * w + 8 * q;

            f32x4 acc0 = {0.f,0.f,0.f,0.f}, acc1 = {0.f,0.f,0.f,0.f};
            f32x4 acc2 = {0.f,0.f,0.f,0.f}, acc3 = {0.f,0.f,0.f,0.f};
            float yn = 0.f;

            float4 y0A = *(const float4*)(bp);
            float4 y1A = *(const float4*)(bp + 4);
            #pragma unroll
            for (int ks = 0; ks < 4; ks++) {
                float4 y0B, y1B;
                if (ks < 3) {
                    y0B = *(const float4*)(bp + (ks + 1) * 32);
                    y1B = *(const float4*)(bp + (ks + 1) * 32 + 4);
                }
                yn = fmaf(y0A.x, y0A.x, fmaf(y0A.y, y0A.y, fmaf(y0A.z, y0A.z, fmaf(y0A.w, y0A.w, yn))));
                yn = fmaf(y1A.x, y1A.x, fmaf(y1A.y, y1A.y, fmaf(y1A.z, y1A.z, fmaf(y1A.w, y1A.w, yn))));
                const f16x8 bf = __builtin_bit_cast(f16x8, pack8(y0A, y1A));
                acc0 = __builtin_amdgcn_mfma_f32_16x16x32_f16(__builtin_bit_cast(f16x8, a[ks][0]), bf, acc0, 0, 0, 0);
                acc1 = __builtin_amdgcn_mfma_f32_16x16x32_f16(__builtin_bit_cast(f16x8, a[ks][1]), bf, acc1, 0, 0, 0);
                acc2 = __builtin_amdgcn_mfma_f32_16x16x32_f16(__builtin_bit_cast(f16x8, a[ks][2]), bf, acc2, 0, 0, 0);
                acc3 = __builtin_amdgcn_mfma_f32_16x16x32_f16(__builtin_bit_cast(f16x8, a[ks][3]), bf, acc3, 0, 0, 0);
                if (ks < 3) { y0A = y0B; y1A = y1B; }
            }

            // fold this wave's k-quarter partials into slds[p] (exact int32)
            float ys = yn;
            ys += __shfl_xor(ys, 16);
            ys += __shfl_xor(ys, 32);
            const int nloc = nsub * 16 + li;
            if (q == 0) atomicAdd(&slds[p][nloc][64], __float2int_rn(ys * SCALE));
            #pragma unroll
            for (int jj = 0; jj < 4; jj++) {
                atomicAdd(&slds[p][nloc][ 0 + 4 * q + jj], __float2int_rn(acc0[jj] * SCALE));
                atomicAdd(&slds[p][nloc][16 + 4 * q + jj], __float2int_rn(acc1[jj] * SCALE));
                atomicAdd(&slds[p][nloc][32 + 4 * q + jj], __float2int_rn(acc2[jj] * SCALE));
                atomicAdd(&slds[p][nloc][48 + 4 * q + jj], __float2int_rn(acc3[jj] * SCALE));
            }
        }

        // overlapped: rotating wave scans tile sc-1 from the OTHER buffer
        if (sc > 0 && w == ((sc - 1) & 3)) scan(sc - 1);

        // ONE barrier per tile: orders (i) this tile's atomics for next
        // phase's scan, (ii) scan's zeroing for tile sc+1's atomics.
        asm volatile("s_waitcnt lgkmcnt(0)");
        __builtin_amdgcn_sched_barrier(0);
        __builtin_amdgcn_s_barrier();
        __builtin_amdgcn_sched_barrier(0);
    }

    // epilogue: scan the final tile
    if (sc > 0 && w == ((sc - 1) & 3)) scan(sc - 1);
    __syncthreads();

    if (tid < 64) {
        const int c = cntS[tid];
        const size_t base = ((size_t)b * 64 + tid) * 16;
        for (int j = 0; j < 16; j++) {
            cs[base + j] = (j < c) ? ((float)topdI[j][tid] * (1.0f / SCALE)) : INF_F;
            ci[base + j] = (j < c) ? topiI[j][tid] : INF_I;
        }
    }
}

// ---------------------------------------------------------------------------
// Kernel 2 (R10 verbatim): approx global top-24 merge, fp64 exact recompute,
// exact sort -> top-16, softmax weights, action gather, outputs.
// ---------------------------------------------------------------------------
__global__ __launch_bounds__(256) void merge_kernel(
    const float* __restrict__ cs, const int* __restrict__ ci,
    const float* __restrict__ brep, const float* __restrict__ reps,
    const float* __restrict__ acts,
    float* __restrict__ out, int NLISTS, int N, int BA)
{
    const int r = blockIdx.x;
    const int tid = threadIdx.x;
    __shared__ __align__(16) float xrow[512];
    __shared__ float S1s[256 * KM];
    __shared__ int   S1i[256 * KM];
    __shared__ float S2s[32 * KM];
    __shared__ int   S2i[32 * KM];
    __shared__ double fd[KM];
    __shared__ int    fn[KM];

    if (tid < 128)
        *(float4*)(&xrow[tid * 4]) = *(const float4*)(&brep[(size_t)r * 512 + tid * 4]);

    float ls[KM]; int li[KM];
    #pragma unroll
    for (int j = 0; j < KM; j++) { ls[j] = INF_F; li[j] = INF_I; }
    float mv = INF_F; int mn = INF_I; int mp = 0;
    const int total = NLISTS * 16;
    for (int e = tid; e < total; e += 256) {
        const int blk = e >> 4, j = e & 15;
        const size_t a = (size_t)blk * 1024 + (size_t)r * 16 + j;
        const float s = cs[a]; const int n = ci[a];
        if (lexLess(s, n, mv, mn)) {
            ls[mp] = s; li[mp] = n;
            mv = ls[0]; mn = li[0]; mp = 0;
            #pragma unroll
            for (int u = 1; u < KM; u++)
                if (!lexLess(ls[u], li[u], mv, mn)) { mv = ls[u]; mn = li[u]; mp = u; }
        }
    }
    #pragma unroll
    for (int j = 0; j < KM; j++) { S1s[tid * KM + j] = ls[j]; S1i[tid * KM + j] = li[j]; }
    __syncthreads();

    if (tid < 32) {
        #pragma unroll
        for (int j = 0; j < KM; j++) { ls[j] = INF_F; li[j] = INF_I; }
        mv = INF_F; mn = INF_I; mp = 0;
        for (int e = tid * 8 * KM; e < (tid * 8 + 8) * KM; e++) {
            const float s = S1s[e]; const int n = S1i[e];
            if (lexLess(s, n, mv, mn)) {
                ls[mp] = s; li[mp] = n;
                mv = ls[0]; mn = li[0]; mp = 0;
                #pragma unroll
                for (int u = 1; u < KM; u++)
                    if (!lexLess(ls[u], li[u], mv, mn)) { mv = ls[u]; mn = li[u]; mp = u; }
            }
        }
        #pragma unroll
        for (int j = 0; j < KM; j++) { S2s[tid * KM + j] = ls[j]; S2i[tid * KM + j] = li[j]; }
    }
    __syncthreads();

    if (tid == 0) {
        #pragma unroll
        for (int j = 0; j < KM; j++) { ls[j] = INF_F; li[j] = INF_I; }
        mv = INF_F; mn = INF_I; mp = 0;
        for (int e = 0; e < 32 * KM; e++) {
            const float s = S2s[e]; const int n = S2i[e];
            if (lexLess(s, n, mv, mn)) {
                ls[mp] = s; li[mp] = n;
                mv = ls[0]; mn = li[0]; mp = 0;
                #pragma unroll
                for (int u = 1; u < KM; u++)
                    if (!lexLess(ls[u], li[u], mv, mn)) { mv = ls[u]; mn = li[u]; mp = u; }
            }
        }
        for (int j = 0; j < KM; j++) fn[j] = li[j];
    }
    __syncthreads();

    if (tid < KM) {
        const int n = fn[tid];
        double d = 1.0e300;
        if (n >= 0 && n < N) {
            double d0a = 0.0, d1a = 0.0, d2a = 0.0, d3a = 0.0;
            const float* yp = reps + (size_t)n * 512;
            for (int i = 0; i < 512; i += 4) {
                float4 yv = *(const float4*)(yp + i);
                double e0 = (double)xrow[i + 0] - (double)yv.x;
                double e1 = (double)xrow[i + 1] - (double)yv.y;
                double e2 = (double)xrow[i + 2] - (double)yv.z;
                double e3 = (double)xrow[i + 3] - (double)yv.w;
                d0a += e0 * e0; d1a += e1 * e1; d2a += e2 * e2; d3a += e3 * e3;
            }
            d = (d0a + d1a) + (d2a + d3a);
        }
        fd[tid] = d;
    }
    __syncthreads();

    if (tid == 0) {
        int ord[KM];
        for (int j = 0; j < KM; j++) ord[j] = j;
        for (int a = 0; a < 16; a++) {
            int best = a;
            for (int u = a + 1; u < KM; u++) {
                const int ou = ord[u], ob = ord[best];
                if (fd[ou] < fd[ob] || (fd[ou] == fd[ob] && fn[ou] < fn[ob])) best = u;
            }
            int tmp = ord[a]; ord[a] = ord[best]; ord[best] = tmp;
        }
        double dist[16];
        for (int j = 0; j < 16; j++) {
            double v = fd[ord[j]];
            dist[j] = sqrt(v > 0.0 ? v : 0.0);
        }
        double wv[16], wsum = 0.0;
        for (int j = 0; j < 16; j++) { wv[j] = exp(dist[0] - dist[j]); wsum += wv[j]; }
        for (int a = 0; a < 7; a++) {
            double s = 0.0;
            for (int j = 0; j < 16; j++)
                s += wv[j] * (double)acts[(size_t)fn[ord[j]] * 7 + a];
            out[r * 7 + a] = (float)(s / wsum);
        }
        for (int j = 0; j < 16; j++)
            out[BA + r * 16 + j] = (float)fn[ord[j]];
    }
}

extern "C" void kernel_launch(void* const* d_in, const int* in_sizes, int n_in,
                              void* d_out, int out_size, void* d_ws, size_t ws_size,
                              hipStream_t stream) {
    const float* brep = (const float*)d_in[0];
    const float* reps = (const float*)d_in[1];
    const float* acts = (const float*)d_in[2];
    const int D = 512;
    const int B = in_sizes[0] / D;   // 64
    const int N = in_sizes[1] / D;   // 500000
    float* out = (float*)d_out;

    // 1024 blocks = 4/CU (25.6 KB LDS, ~110 VGPR pinned by waves_per_eu(4,4)).
    int NBLK = 1024;
    const size_t perblk = (size_t)64 * 16 * 8;        // cs+ci bytes per block
    while (NBLK > 1 && (size_t)NBLK * perblk > ws_size) NBLK >>= 1;

    float* cs = (float*)d_ws;
    int* ci = (int*)((char*)d_ws + (size_t)NBLK * 64 * 16 * 4);

    const int TT = (N + 31) / 32;                     // 32-row tiles

    dist_topk_kernel<<<NBLK, 256, 0, stream>>>(reps, brep, cs, ci, N, TT, NBLK);
    merge_kernel<<<B, 256, 0, stream>>>(cs, ci, brep, reps, acts, out, NBLK, N, B * 7);
}